// Round 6
// baseline (2742.841 us; speedup 1.0000x reference)
//
#include <hip/hip_runtime.h>

#define H 1024
#define I_DIM 128
#define O_DIM 128
#define T_DIM 512
#define ALPHA 0.2f
#define NWG 64          // 4 batch-groups x 16 j-slices
#define GSZ 16          // WGs per batch-group

typedef short short8 __attribute__((ext_vector_type(8)));
typedef float f32x4 __attribute__((ext_vector_type(4)));
typedef unsigned long long ull_alias __attribute__((may_alias));

__device__ __forceinline__ unsigned short f2b(float f) {
    union { float f; unsigned u; } x; x.f = f;
    unsigned u = x.u;
    return (unsigned short)((u + 0x7FFFu + ((u >> 16) & 1u)) >> 16);
}
__device__ __forceinline__ float tanh_fast(float x) {
    float e = __expf(2.0f * x);
    return 1.0f - 2.0f * __builtin_amdgcn_rcpf(e + 1.0f);
}
// 8 contiguous f32 -> bf16 fragment (RNE)
__device__ __forceinline__ short8 ld8f(const float* __restrict__ p) {
    const float4 a = *(const float4*)p;
    const float4 b = *(const float4*)(p + 4);
    short8 r;
    r[0]=(short)f2b(a.x); r[1]=(short)f2b(a.y); r[2]=(short)f2b(a.z); r[3]=(short)f2b(a.w);
    r[4]=(short)f2b(b.x); r[5]=(short)f2b(b.y); r[6]=(short)f2b(b.z); r[7]=(short)f2b(b.w);
    return r;
}
__device__ __forceinline__ void async16(const unsigned short* g, unsigned short* l) {
    __builtin_amdgcn_global_load_lds(
        (const __attribute__((address_space(1))) unsigned int*)(const void*)g,
        (__attribute__((address_space(3))) unsigned int*)(void*)l, 16, 0, 0);
}

// Packed-A layout per batch-group: A[m][k] at u16 offset
//   (k>>5)*512 + ((k&31)>>3)*128 + m*8 + (k&7)
// Wave w of WG ji produces k in [ji*64 + w*16, ...+16): its staged data is the
// contiguous u16 range [w*256, w*256+256) of the WG's 2 KB slice -> wave-private
// publish with no cross-wave sync. Tags are per (ji,w): 64 tags per group/parity.
__global__ __launch_bounds__(256, 1) void rnn_kernel(
    const float* __restrict__ x, const float* __restrict__ wi,
    const float* __restrict__ wrec, const float* __restrict__ wout,
    const float* __restrict__ bb, const float* __restrict__ gg,
    const float* __restrict__ h0p, float* __restrict__ out,
    unsigned short* __restrict__ aG, unsigned int* __restrict__ tagG)
{
    __shared__ unsigned short abuf[32 * 512];   // 32 KB: group's full a_{t-1}
    __shared__ unsigned short aloc[1024];       // 2 KB: own a_t slice, packed
    __shared__ float opart[4 * 128];            // 2 KB: out k-partials

    const int tid  = threadIdx.x;
    const int w    = tid >> 6, lane = tid & 63;
    const int n    = lane & 15, q = lane >> 4;
    const int grp  = blockIdx.x & 3;
    const int ji   = blockIdx.x >> 2;
    const int j0   = ji * 64;
    const int j    = j0 + w * 16 + n;           // this lane's owned h row
    const int b0   = grp * 16;
    unsigned int* tg = tagG + grp * 128;        // [parity][64] tags for this group

    // ---- register-resident weights (f32 -> bf16, once) ----
    short8 wfr[32];                              // wrec B-frags: B[k][j] = wrec[j][k]
#pragma unroll
    for (int kt = 0; kt < 32; ++kt)
        wfr[kt] = ld8f(&wrec[(size_t)j * H + kt * 32 + q * 8]);

    short8 wifr[4];                              // wi B-frags: B[k][j] = wi[k][j]
#pragma unroll
    for (int kt = 0; kt < 4; ++kt) {
        short8 v;
#pragma unroll
        for (int i = 0; i < 8; ++i)
            v[i] = (short)f2b(wi[(size_t)(kt * 32 + q * 8 + i) * H + j]);
        wifr[kt] = v;
    }
    short8 wofr[8];                              // wout B-frags, cols ji*8..+8, zero-pad n>=8
#pragma unroll
    for (int kk = 0; kk < 8; ++kk) {
        short8 v;
        const int kb = (w * 8 + kk) * 32 + q * 8;
#pragma unroll
        for (int i = 0; i < 8; ++i)
            v[i] = (n < 8) ? (short)f2b(wout[(size_t)(kb + i) * O_DIM + ji * 8 + n]) : (short)0;
        wofr[kk] = v;
    }

    const float gv = gg[j], bv = bb[j], h00 = h0p[j];
    float hreg[4];
#pragma unroll
    for (int r = 0; r < 4; ++r) hreg[r] = h00;

    const int kl    = w * 16 + n;                // local k in [0,64)
    const int off_l = (kl >> 5) * 512 + ((kl & 31) >> 3) * 128 + (kl & 7);
    const int slot  = ji * 4 + w;                // this wave's tag slot

    // wave-private publish: 512 B from aloc[w*256 ..) -> aG slice, write-through.
    // The compiler barrier + may_alias read type force the ds_read of aloc to
    // stay BELOW this iteration's aloc ds_writes (same-wave DS ops execute in
    // order in HW; the hazard is compile-time reordering via TBAA).
    auto publish = [&](int t) {
        asm volatile("" ::: "memory");
        unsigned long long v = *(const ull_alias*)&aloc[w * 256 + lane * 4];
        unsigned long long* dst = (unsigned long long*)
            (aG + (size_t)((t & 1) * 4 + grp) * 16384 + ji * 1024 + w * 256 + lane * 4);
        __hip_atomic_store(dst, v, __ATOMIC_RELAXED, __HIP_MEMORY_SCOPE_AGENT);
        asm volatile("s_waitcnt vmcnt(0)" ::: "memory");
        if (lane == 0)
            __hip_atomic_store(&tg[(t & 1) * 64 + slot], (unsigned)t,
                               __ATOMIC_RELAXED, __HIP_MEMORY_SCOPE_AGENT);
    };

    // out[:, t, ji*8..+8) from abuf (full k=1024 chain)
    auto do_out = [&](int t) {
        f32x4 oa = {0.f, 0.f, 0.f, 0.f};
#pragma unroll
        for (int kk = 0; kk < 8; ++kk) {
            short8 af = *(const short8*)&abuf[(w * 8 + kk) * 512 + lane * 8];
            oa = __builtin_amdgcn_mfma_f32_16x16x32_bf16(af, wofr[kk], oa, 0, 0, 0);
        }
        if (n < 8) {
#pragma unroll
            for (int r = 0; r < 4; ++r) opart[w * 128 + (4 * q + r) * 8 + n] = oa[r];
        }
        __syncthreads();
        if (tid < 128) {
            float s = opart[tid] + opart[128 + tid] + opart[256 + tid] + opart[384 + tid];
            const int m = tid >> 3, c = tid & 7;
            out[((size_t)(b0 + m) * T_DIM + t) * O_DIM + ji * 8 + c] = s;
        }
    };

    // per-wave wait: all 64 tags of parity p == tv, then ONE acquire (buffer_inv)
    auto wait_tags = [&](int tv) {
        const unsigned int* tp = tg + (tv & 1) * 64;
        for (;;) {
            unsigned v = __hip_atomic_load(&tp[lane], __ATOMIC_RELAXED,
                                           __HIP_MEMORY_SCOPE_AGENT);
            if (__all(v == (unsigned)tv)) break;
            __builtin_amdgcn_s_sleep(1);
        }
        (void)__hip_atomic_load(&tp[0], __ATOMIC_ACQUIRE, __HIP_MEMORY_SCOPE_AGENT);
    };

    // ---- init: stage + publish a0 = g*tanh(h0+b) (batch-broadcast) ----
    {
        unsigned short a0 = f2b(gv * tanh_fast(h00 + bv));
#pragma unroll
        for (int r = 0; r < 4; ++r) aloc[off_l + (4 * q + r) * 8] = a0;
        publish(0);
    }

    short8 xfr[4];                               // prefetch x[:,0,:]
#pragma unroll
    for (int kt = 0; kt < 4; ++kt)
        xfr[kt] = ld8f(&x[(size_t)(b0 + n) * T_DIM * I_DIM + kt * 32 + q * 8]);

    for (int t = 1; t < T_DIM; ++t) {
        // x@wi partials: register-only, overlaps stragglers
        f32x4 acc0 = {0.f,0.f,0.f,0.f}, acc1 = {0.f,0.f,0.f,0.f};
        acc0 = __builtin_amdgcn_mfma_f32_16x16x32_bf16(xfr[0], wifr[0], acc0, 0,0,0);
        acc1 = __builtin_amdgcn_mfma_f32_16x16x32_bf16(xfr[1], wifr[1], acc1, 0,0,0);
        acc0 = __builtin_amdgcn_mfma_f32_16x16x32_bf16(xfr[2], wifr[2], acc0, 0,0,0);
        acc1 = __builtin_amdgcn_mfma_f32_16x16x32_bf16(xfr[3], wifr[3], acc1, 0,0,0);

        __syncthreads();          // all waves done reading old abuf (do_out t-2)
        wait_tags(t - 1);         // per-wave spin, relaxed; one acquire at exit

        // a_{t-1} (32 KB packed) -> LDS; wave w loads chunks 8w..8w+7
        const unsigned short* src = aG + (size_t)(((t - 1) & 1) * 4 + grp) * 16384;
#pragma unroll
        for (int c = 0; c < 8; ++c) {
            const int chunk = w * 8 + c;
            async16(src + chunk * 512 + lane * 8, abuf + chunk * 512);
        }
        __syncthreads();          // all chunks visible to all waves

        // + a_{t-1} @ wrec^T
#pragma unroll
        for (int kt = 0; kt < 32; kt += 2) {
            short8 a0f = *(const short8*)&abuf[kt * 512 + lane * 8];
            short8 a1f = *(const short8*)&abuf[(kt + 1) * 512 + lane * 8];
            acc0 = __builtin_amdgcn_mfma_f32_16x16x32_bf16(a0f, wfr[kt],     acc0, 0,0,0);
            acc1 = __builtin_amdgcn_mfma_f32_16x16x32_bf16(a1f, wfr[kt + 1], acc1, 0,0,0);
        }

        // h update; stage a_t in aloc (wave-private region), publish immediately
#pragma unroll
        for (int r = 0; r < 4; ++r) {
            float z  = acc0[r] + acc1[r];
            float hv = (1.0f - ALPHA) * hreg[r] + ALPHA * z;
            hreg[r] = hv;
            aloc[off_l + (4 * q + r) * 8] = f2b(gv * tanh_fast(hv + bv));
        }
        publish(t);               // compiler barrier inside keeps order vs aloc writes

        // off critical path: x prefetch + out for step t-1
        if (t < T_DIM - 1) {
#pragma unroll
            for (int kt = 0; kt < 4; ++kt)
                xfr[kt] = ld8f(&x[((size_t)(b0 + n) * T_DIM + t) * I_DIM + kt * 32 + q * 8]);
        }
        do_out(t - 1);
    }

    // epilogue: out[:, 511, :] from a_511
    __syncthreads();
    wait_tags(T_DIM - 1);
    const unsigned short* src = aG + (size_t)(((T_DIM - 1) & 1) * 4 + grp) * 16384;
#pragma unroll
    for (int c = 0; c < 8; ++c) {
        const int chunk = w * 8 + c;
        async16(src + chunk * 512 + lane * 8, abuf + chunk * 512);
    }
    __syncthreads();
    do_out(T_DIM - 1);
}

extern "C" void kernel_launch(void* const* d_in, const int* in_sizes, int n_in,
                              void* d_out, int out_size, void* d_ws, size_t ws_size,
                              hipStream_t stream) {
    const float* x    = (const float*)d_in[0];
    const float* wi   = (const float*)d_in[1];
    const float* wrec = (const float*)d_in[2];
    const float* wout = (const float*)d_in[3];
    const float* bb   = (const float*)d_in[4];
    const float* gg   = (const float*)d_in[5];
    const float* h0   = (const float*)d_in[6];
    float* outp = (float*)d_out;

    unsigned short* aG = (unsigned short*)d_ws;                  // 2 x 4 x 32 KB = 256 KB
    unsigned int* tagG = (unsigned int*)((char*)d_ws + 2 * 4 * 16384 * 2);  // 4x2x64 u32

    hipMemsetAsync(tagG, 0xFF, 4 * 2 * 64 * sizeof(unsigned int), stream);
    hipLaunchKernelGGL(rnn_kernel, dim3(NWG), dim3(256), 0, stream,
                       x, wi, wrec, wout, bb, gg, h0, outp, aG, tagG);
}

// Round 7
// 1976.829 us; speedup vs baseline: 1.3875x; 1.3875x over previous
//
#include <hip/hip_runtime.h>

#define H 1024
#define I_DIM 128
#define O_DIM 128
#define T_DIM 512
#define ALPHA 0.2f
#define NWG 64          // 4 batch-groups x 16 j-slices
#define GSZ 16          // WGs per batch-group

typedef short short8 __attribute__((ext_vector_type(8)));
typedef float f32x4 __attribute__((ext_vector_type(4)));
typedef unsigned long long ull_alias __attribute__((may_alias));

__device__ __forceinline__ unsigned short f2b(float f) {
    union { float f; unsigned u; } x; x.f = f;
    unsigned u = x.u;
    return (unsigned short)((u + 0x7FFFu + ((u >> 16) & 1u)) >> 16);
}
__device__ __forceinline__ float tanh_fast(float x) {
    float e = __expf(2.0f * x);
    return 1.0f - 2.0f * __builtin_amdgcn_rcpf(e + 1.0f);
}
// 8 contiguous f32 -> bf16 fragment (RNE)
__device__ __forceinline__ short8 ld8f(const float* __restrict__ p) {
    const float4 a = *(const float4*)p;
    const float4 b = *(const float4*)(p + 4);
    short8 r;
    r[0]=(short)f2b(a.x); r[1]=(short)f2b(a.y); r[2]=(short)f2b(a.z); r[3]=(short)f2b(a.w);
    r[4]=(short)f2b(b.x); r[5]=(short)f2b(b.y); r[6]=(short)f2b(b.z); r[7]=(short)f2b(b.w);
    return r;
}

// Packed-A layout per batch-group: A[m][k] at u16 offset
//   (k>>5)*512 + ((k&31)>>3)*128 + m*8 + (k&7)
// Wave w of WG ji produces k in [ji*64 + w*16, ...+16): contiguous 512 B of the
// WG's 2 KB slice -> wave-private publish. Tags per (ji,w): 64 per group/parity.
// ALL cross-WG data moves via relaxed agent-scope atomics (coherent at the LLC,
// no buffer_inv / buffer_wbl2 anywhere in the loop).
__global__ __launch_bounds__(256, 1) void rnn_kernel(
    const float* __restrict__ x, const float* __restrict__ wi,
    const float* __restrict__ wrec, const float* __restrict__ wout,
    const float* __restrict__ bb, const float* __restrict__ gg,
    const float* __restrict__ h0p, float* __restrict__ out,
    unsigned short* __restrict__ aG, unsigned int* __restrict__ tagG)
{
    __shared__ unsigned short abuf[32 * 512];   // 32 KB: group's full a_{t-1}
    __shared__ unsigned short aloc[1024];       // 2 KB: own a_t slice, packed
    __shared__ float opart[4 * 128];            // 2 KB: out k-partials

    const int tid  = threadIdx.x;
    const int w    = tid >> 6, lane = tid & 63;
    const int n    = lane & 15, q = lane >> 4;
    const int grp  = blockIdx.x & 3;
    const int ji   = blockIdx.x >> 2;
    const int j0   = ji * 64;
    const int j    = j0 + w * 16 + n;           // this lane's owned h row
    const int b0   = grp * 16;
    unsigned int* tg = tagG + grp * 128;        // [parity][64] tags for this group

    // ---- register-resident weights (f32 -> bf16, once) ----
    short8 wfr[32];                              // wrec B-frags: B[k][j] = wrec[j][k]
#pragma unroll
    for (int kt = 0; kt < 32; ++kt)
        wfr[kt] = ld8f(&wrec[(size_t)j * H + kt * 32 + q * 8]);

    short8 wifr[4];                              // wi B-frags: B[k][j] = wi[k][j]
#pragma unroll
    for (int kt = 0; kt < 4; ++kt) {
        short8 v;
#pragma unroll
        for (int i = 0; i < 8; ++i)
            v[i] = (short)f2b(wi[(size_t)(kt * 32 + q * 8 + i) * H + j]);
        wifr[kt] = v;
    }
    short8 wofr[8];                              // wout B-frags, cols ji*8..+8, zero-pad n>=8
#pragma unroll
    for (int kk = 0; kk < 8; ++kk) {
        short8 v;
        const int kb = (w * 8 + kk) * 32 + q * 8;
#pragma unroll
        for (int i = 0; i < 8; ++i)
            v[i] = (n < 8) ? (short)f2b(wout[(size_t)(kb + i) * O_DIM + ji * 8 + n]) : (short)0;
        wofr[kk] = v;
    }

    const float gv = gg[j], bv = bb[j], h00 = h0p[j];
    float hreg[4];
#pragma unroll
    for (int r = 0; r < 4; ++r) hreg[r] = h00;

    const int kl    = w * 16 + n;                // local k in [0,64)
    const int off_l = (kl >> 5) * 512 + ((kl & 31) >> 3) * 128 + (kl & 7);
    const int slot  = ji * 4 + w;                // this wave's tag slot

    // wave-private publish: 512 B from aloc[w*256 ..) -> aG, relaxed agent stores
    auto publish = [&](int t) {
        asm volatile("" ::: "memory");
        unsigned long long v = *(const ull_alias*)&aloc[w * 256 + lane * 4];
        unsigned long long* dst = (unsigned long long*)
            (aG + (size_t)((t & 1) * 4 + grp) * 16384 + ji * 1024 + w * 256 + lane * 4);
        __hip_atomic_store(dst, v, __ATOMIC_RELAXED, __HIP_MEMORY_SCOPE_AGENT);
        asm volatile("s_waitcnt vmcnt(0)" ::: "memory");
        if (lane == 0)
            __hip_atomic_store(&tg[(t & 1) * 64 + slot], (unsigned)t,
                               __ATOMIC_RELAXED, __HIP_MEMORY_SCOPE_AGENT);
    };

    // consume: wave w pulls its 8 KB share of a_{t-1} via relaxed agent atomic
    // loads (LLC-coherent, no cache maintenance), then ds_write_b64 into abuf.
    auto consume = [&](int tv) {
        const ull_alias* s64 = (const ull_alias*)
            (aG + (size_t)((tv & 1) * 4 + grp) * 16384) + (size_t)w * 1024;
        unsigned long long vals[16];
#pragma unroll
        for (int i = 0; i < 16; ++i)
            vals[i] = __hip_atomic_load((const unsigned long long*)&s64[i * 64 + lane],
                                        __ATOMIC_RELAXED, __HIP_MEMORY_SCOPE_AGENT);
        asm volatile("" ::: "memory");
        ull_alias* d64 = (ull_alias*)abuf + (size_t)w * 1024;
#pragma unroll
        for (int i = 0; i < 16; ++i)
            d64[i * 64 + lane] = vals[i];
    };

    // out[:, t, ji*8..+8) from abuf (full k=1024 chain)
    auto do_out = [&](int t) {
        f32x4 oa = {0.f, 0.f, 0.f, 0.f};
#pragma unroll
        for (int kk = 0; kk < 8; ++kk) {
            short8 af = *(const short8*)&abuf[(w * 8 + kk) * 512 + lane * 8];
            oa = __builtin_amdgcn_mfma_f32_16x16x32_bf16(af, wofr[kk], oa, 0, 0, 0);
        }
        if (n < 8) {
#pragma unroll
            for (int r = 0; r < 4; ++r) opart[w * 128 + (4 * q + r) * 8 + n] = oa[r];
        }
        __syncthreads();
        if (tid < 128) {
            float s = opart[tid] + opart[128 + tid] + opart[256 + tid] + opart[384 + tid];
            const int m = tid >> 3, c = tid & 7;
            out[((size_t)(b0 + m) * T_DIM + t) * O_DIM + ji * 8 + c] = s;
        }
    };

    // per-wave wait: all 64 tags of parity == tv. Relaxed only; no acquire.
    auto wait_tags = [&](int tv) {
        const unsigned int* tp = tg + (tv & 1) * 64;
        for (;;) {
            unsigned v = __hip_atomic_load(&tp[lane], __ATOMIC_RELAXED,
                                           __HIP_MEMORY_SCOPE_AGENT);
            if (__all(v == (unsigned)tv)) break;
            __builtin_amdgcn_s_sleep(1);
        }
        asm volatile("" ::: "memory");
    };

    // ---- init: stage + publish a0 = g*tanh(h0+b) (batch-broadcast) ----
    {
        unsigned short a0 = f2b(gv * tanh_fast(h00 + bv));
#pragma unroll
        for (int r = 0; r < 4; ++r) aloc[off_l + (4 * q + r) * 8] = a0;
        publish(0);
    }

    short8 xfr[4];                               // prefetch x[:,0,:]
#pragma unroll
    for (int kt = 0; kt < 4; ++kt)
        xfr[kt] = ld8f(&x[(size_t)(b0 + n) * T_DIM * I_DIM + kt * 32 + q * 8]);

    for (int t = 1; t < T_DIM; ++t) {
        // x@wi partials: register-only, overlaps stragglers
        f32x4 acc0 = {0.f,0.f,0.f,0.f}, acc1 = {0.f,0.f,0.f,0.f};
        acc0 = __builtin_amdgcn_mfma_f32_16x16x32_bf16(xfr[0], wifr[0], acc0, 0,0,0);
        acc1 = __builtin_amdgcn_mfma_f32_16x16x32_bf16(xfr[1], wifr[1], acc1, 0,0,0);
        acc0 = __builtin_amdgcn_mfma_f32_16x16x32_bf16(xfr[2], wifr[2], acc0, 0,0,0);
        acc1 = __builtin_amdgcn_mfma_f32_16x16x32_bf16(xfr[3], wifr[3], acc1, 0,0,0);

        __syncthreads();          // all waves done reading old abuf (do_out t-2)
        wait_tags(t - 1);         // per-wave relaxed spin
        consume(t - 1);           // atomic loads -> VGPR -> ds_write abuf
        __syncthreads();          // abuf complete & visible to all waves

        // + a_{t-1} @ wrec^T
#pragma unroll
        for (int kt = 0; kt < 32; kt += 2) {
            short8 a0f = *(const short8*)&abuf[kt * 512 + lane * 8];
            short8 a1f = *(const short8*)&abuf[(kt + 1) * 512 + lane * 8];
            acc0 = __builtin_amdgcn_mfma_f32_16x16x32_bf16(a0f, wfr[kt],     acc0, 0,0,0);
            acc1 = __builtin_amdgcn_mfma_f32_16x16x32_bf16(a1f, wfr[kt + 1], acc1, 0,0,0);
        }

        // h update; stage a_t in aloc (wave-private region), publish immediately
#pragma unroll
        for (int r = 0; r < 4; ++r) {
            float z  = acc0[r] + acc1[r];
            float hv = (1.0f - ALPHA) * hreg[r] + ALPHA * z;
            hreg[r] = hv;
            aloc[off_l + (4 * q + r) * 8] = f2b(gv * tanh_fast(hv + bv));
        }
        publish(t);

        // off critical path: x prefetch + out for step t-1
        if (t < T_DIM - 1) {
#pragma unroll
            for (int kt = 0; kt < 4; ++kt)
                xfr[kt] = ld8f(&x[((size_t)(b0 + n) * T_DIM + t) * I_DIM + kt * 32 + q * 8]);
        }
        do_out(t - 1);
    }

    // epilogue: out[:, 511, :] from a_511
    __syncthreads();
    wait_tags(T_DIM - 1);
    consume(T_DIM - 1);
    __syncthreads();
    do_out(T_DIM - 1);
}

extern "C" void kernel_launch(void* const* d_in, const int* in_sizes, int n_in,
                              void* d_out, int out_size, void* d_ws, size_t ws_size,
                              hipStream_t stream) {
    const float* x    = (const float*)d_in[0];
    const float* wi   = (const float*)d_in[1];
    const float* wrec = (const float*)d_in[2];
    const float* wout = (const float*)d_in[3];
    const float* bb   = (const float*)d_in[4];
    const float* gg   = (const float*)d_in[5];
    const float* h0   = (const float*)d_in[6];
    float* outp = (float*)d_out;

    unsigned short* aG = (unsigned short*)d_ws;                  // 2 x 4 x 32 KB = 256 KB
    unsigned int* tagG = (unsigned int*)((char*)d_ws + 2 * 4 * 16384 * 2);  // 4x2x64 u32

    hipMemsetAsync(tagG, 0xFF, 4 * 2 * 64 * sizeof(unsigned int), stream);
    hipLaunchKernelGGL(rnn_kernel, dim3(NWG), dim3(256), 0, stream,
                       x, wi, wrec, wout, bb, gg, h0, outp, aG, tagG);
}